// Round 13
// baseline (216.188 us; speedup 1.0000x reference)
//
#include <hip/hip_runtime.h>
#include <hip/hip_bf16.h>
#include <cmath>

#define D_MODEL 512
#define D_INNER 1024
#define NHEAD 16
#define HDIM 64
#define NSTATE 16
#define NB 8
#define NT 64
#define NW 16
#define MROWS 8192      // NB*NT*NW
#define NPROJ 2096

typedef __attribute__((ext_vector_type(8))) short short8;
typedef __attribute__((ext_vector_type(4))) float f32x4;
typedef __hip_bfloat16 bf16;
typedef unsigned int u32;
typedef unsigned short u16;

__device__ __forceinline__ u32 fbits(float f) { return __float_as_uint(f); }
__device__ __forceinline__ float ubits(u32 u) { return __uint_as_float(u); }
__device__ __forceinline__ u32 pack_bf(float a, float b) {
  return (fbits(b) & 0xffff0000u) | (fbits(a) >> 16);
}

// counted vmcnt wait (literal immediates; "memory" clobber = compiler fence)
template<int N> __device__ __forceinline__ void vmwait() {
  if constexpr (N == 0)      asm volatile("s_waitcnt vmcnt(0)" ::: "memory");
  else if constexpr (N == 2) asm volatile("s_waitcnt vmcnt(2)" ::: "memory");
  else if constexpr (N == 3) asm volatile("s_waitcnt vmcnt(3)" ::: "memory");
  else if constexpr (N == 4) asm volatile("s_waitcnt vmcnt(4)" ::: "memory");
  else if constexpr (N == 6) asm volatile("s_waitcnt vmcnt(6)" ::: "memory");
  else if constexpr (N == 8) asm volatile("s_waitcnt vmcnt(8)" ::: "memory");
  else static_assert(N == 0, "unsupported vmcnt");
}

// ---------------- block-wide sum reduction (256 threads = 4 waves) ----------
__device__ __forceinline__ float block_sum(float v, float* sbuf) {
#pragma unroll
  for (int o = 32; o > 0; o >>= 1) v += __shfl_down(v, o, 64);
  int lane = threadIdx.x & 63, wid = threadIdx.x >> 6;
  if (lane == 0) sbuf[wid] = v;
  __syncthreads();
  if (threadIdx.x == 0) {
    float t = 0.f;
    for (int i = 0; i < 4; i++) t += sbuf[i];
    sbuf[0] = t;
  }
  __syncthreads();
  return sbuf[0];
}

// ---------------- LayerNorm over 512, bf16 out ------------------------------
__global__ __launch_bounds__(256) void ln512_bf16_kernel(
    const float* __restrict__ x, const float* __restrict__ w,
    const float* __restrict__ b, bf16* __restrict__ out) {
  __shared__ float s1[8], s2[8];
  int row = blockIdx.x;
  const float* xr = x + (size_t)row * D_MODEL;
  bf16* outr = out + (size_t)row * D_MODEL;
  int c0 = threadIdx.x, c1 = threadIdx.x + 256;
  float v0 = xr[c0], v1 = xr[c1];
  float s  = block_sum(v0 + v1, s1);
  float ss = block_sum(v0 * v0 + v1 * v1, s2);
  float mean = s * (1.f / 512.f);
  float var  = ss * (1.f / 512.f) - mean * mean;
  float inv  = rsqrtf(var + 1e-5f);
  outr[c0] = __float2bfloat16((v0 - mean) * inv * w[c0] + b[c0]);
  outr[c1] = __float2bfloat16((v1 - mean) * inv * w[c1] + b[c1]);
}

// ---------------- merged weight convert+transpose (4 configs in 1 grid) -----
// out_w gets norm_w folded in (scale by norm_w[k]).
__global__ __launch_bounds__(256) void wconv_all_kernel(
    const float* __restrict__ in_w, bf16* __restrict__ in_wt,
    const float* __restrict__ out_w, bf16* __restrict__ out_wt,
    const float* __restrict__ norm_w,
    const float* __restrict__ ff1_w, bf16* __restrict__ ff1_wt,
    const float* __restrict__ ff2_w, bf16* __restrict__ ff2_wt) {
  __shared__ float tile[32][33];
  int id = blockIdx.x;
  const float* w; bf16* wt; const float* sc = nullptr;
  int K, N, Npad, bx, by;
  if (id < 1088)      { w = in_w;  wt = in_wt;  K = 512;  N = NPROJ; Npad = 2176; bx = id % 68;  by = id / 68; }
  else if (id < 1600) { int j = id - 1088; w = out_w; wt = out_wt; sc = norm_w; K = 1024; N = 512;  Npad = 512;  bx = j % 16; by = j / 16; }
  else if (id < 2624) { int j = id - 1600; w = ff1_w; wt = ff1_wt; K = 512;  N = 2048; Npad = 2048; bx = j % 64; by = j / 64; }
  else                { int j = id - 2624; w = ff2_w; wt = ff2_wt; K = 1024; N = 512;  Npad = 512;  bx = j % 16; by = j / 16; }
  int n0 = bx * 32, k0 = by * 32;
  int tx = threadIdx.x & 31, ty = threadIdx.x >> 5;  // 32 x 8
#pragma unroll
  for (int i = 0; i < 4; i++) {
    int k = k0 + ty + i * 8, n = n0 + tx;
    tile[ty + i * 8][tx] = (k < K && n < N) ? w[(size_t)k * N + n] : 0.f;
  }
  __syncthreads();
  float s = sc ? sc[k0 + tx] : 1.f;
#pragma unroll
  for (int i = 0; i < 4; i++) {
    int n = n0 + ty + i * 8, k = k0 + tx;
    if (n < Npad && k < K)
      wt[(size_t)n * K + k] = __float2bfloat16(tile[tx][ty + i * 8] * s);
  }
}

// ---------------- fp32-out MFMA GEMM, 3-buffer counted-vmcnt pipeline -------
template<int BM, int BN, int WN, int MR, int NR>
__global__ __launch_bounds__(256) void mfma_gemm_kernel(
    const bf16* __restrict__ A, const bf16* __restrict__ Bt,
    const float* __restrict__ bias, int nbias,
    const float* __restrict__ resid,
    float* __restrict__ C, int ldc, int K) {
  constexpr int ROWS = BM + BN;
  constexpr int ISS  = ROWS / 64;
  __shared__ __align__(16) bf16 sAB[3][ROWS][32];

  int wid = threadIdx.x >> 6, lane = threadIdx.x & 63;
  int row0 = blockIdx.y * BM, col0 = blockIdx.x * BN;
  int wr = (wid / WN) * (MR * 16);
  int wc = (wid % WN) * (NR * 16);
  int lr = lane >> 2;
  int lc = (lane & 3) * 8;

  f32x4 acc[MR][NR];
#pragma unroll
  for (int m = 0; m < MR; m++)
#pragma unroll
    for (int n = 0; n < NR; n++) acc[m][n] = (f32x4){0.f, 0.f, 0.f, 0.f};

  auto stage = [&](int buf, int k0) {
#pragma unroll
    for (int i = 0; i < ISS; i++) {
      int rb = (wid * ISS + i) * 16;
      int r = rb + lr;
      const bf16* src = (r < BM)
          ? A  + (size_t)(row0 + r) * K + k0 + lc
          : Bt + (size_t)(col0 + (r - BM)) * K + k0 + lc;
      __builtin_amdgcn_global_load_lds(
          (const __attribute__((address_space(1))) void*)src,
          (__attribute__((address_space(3))) void*)&sAB[buf][rb][0], 16, 0, 0);
    }
  };

  stage(0, 0);
  stage(1, 32);
  int cur = 0;
  for (int k0 = 0; k0 < K; k0 += 32) {
    if (k0 + 32 < K) vmwait<ISS>(); else vmwait<0>();
    __builtin_amdgcn_s_barrier();
    asm volatile("" ::: "memory");
    if (k0 + 64 < K) stage(cur == 0 ? 2 : cur - 1, k0 + 64);
    short8 a[MR], b[NR];
    int kk = (lane >> 4) * 8;
#pragma unroll
    for (int m = 0; m < MR; m++)
      a[m] = *(const short8*)&sAB[cur][wr + m * 16 + (lane & 15)][kk];
#pragma unroll
    for (int n = 0; n < NR; n++)
      b[n] = *(const short8*)&sAB[cur][BM + wc + n * 16 + (lane & 15)][kk];
#pragma unroll
    for (int m = 0; m < MR; m++)
#pragma unroll
      for (int n = 0; n < NR; n++)
        acc[m][n] = __builtin_amdgcn_mfma_f32_16x16x32_bf16(a[m], b[n], acc[m][n], 0, 0, 0);
    asm volatile("" ::: "memory");
    cur = (cur == 2) ? 0 : cur + 1;
  }

  int crow = row0 + wr + (lane >> 4) * 4;
  int ccol = col0 + wc + (lane & 15);
#pragma unroll
  for (int m = 0; m < MR; m++) {
#pragma unroll
    for (int n = 0; n < NR; n++) {
      int colg = ccol + n * 16;
      float bv = bias ? ((colg < nbias) ? bias[colg] : 0.f) : 0.f;
#pragma unroll
      for (int j = 0; j < 4; j++) {
        int rowg = crow + m * 16 + j;
        float v = acc[m][n][j] + bv;
        if (resid) v += resid[(size_t)rowg * ldc + colg];
        C[(size_t)rowg * ldc + colg] = v;
      }
    }
  }
}

// ---------------- in-proj GEMM (3-buf): z->zb, x->xsc (scan layout), aux ----
__global__ __launch_bounds__(256) void inproj_gemm_kernel(
    const bf16* __restrict__ A, const bf16* __restrict__ Bt,
    const float* __restrict__ bias,
    bf16* __restrict__ zb, bf16* __restrict__ xsc,
    float* __restrict__ aux, int K) {
  constexpr int BM = 128, ROWS = 256, ISS = 4;
  __shared__ __align__(16) bf16 sAB[3][ROWS][32];

  int wid = threadIdx.x >> 6, lane = threadIdx.x & 63;
  int row0 = blockIdx.y * BM, col0 = blockIdx.x * 128;
  int wr = (wid >> 1) * 64;
  int wc = (wid & 1) * 64;
  int lr = lane >> 2;
  int lc = (lane & 3) * 8;

  f32x4 acc[4][4];
#pragma unroll
  for (int m = 0; m < 4; m++)
#pragma unroll
    for (int n = 0; n < 4; n++) acc[m][n] = (f32x4){0.f, 0.f, 0.f, 0.f};

  auto stage = [&](int buf, int k0) {
#pragma unroll
    for (int i = 0; i < ISS; i++) {
      int rb = (wid * ISS + i) * 16;
      int r = rb + lr;
      const bf16* src = (r < BM)
          ? A  + (size_t)(row0 + r) * K + k0 + lc
          : Bt + (size_t)(col0 + (r - BM)) * K + k0 + lc;
      __builtin_amdgcn_global_load_lds(
          (const __attribute__((address_space(1))) void*)src,
          (__attribute__((address_space(3))) void*)&sAB[buf][rb][0], 16, 0, 0);
    }
  };

  stage(0, 0);
  stage(1, 32);
  int cur = 0;
  for (int k0 = 0; k0 < K; k0 += 32) {
    if (k0 + 32 < K) vmwait<ISS>(); else vmwait<0>();
    __builtin_amdgcn_s_barrier();
    asm volatile("" ::: "memory");
    if (k0 + 64 < K) stage(cur == 0 ? 2 : cur - 1, k0 + 64);
    short8 a[4], b[4];
    int kk = (lane >> 4) * 8;
#pragma unroll
    for (int m = 0; m < 4; m++)
      a[m] = *(const short8*)&sAB[cur][wr + m * 16 + (lane & 15)][kk];
#pragma unroll
    for (int n = 0; n < 4; n++)
      b[n] = *(const short8*)&sAB[cur][BM + wc + n * 16 + (lane & 15)][kk];
#pragma unroll
    for (int m = 0; m < 4; m++)
#pragma unroll
      for (int n = 0; n < 4; n++)
        acc[m][n] = __builtin_amdgcn_mfma_f32_16x16x32_bf16(a[m], b[n], acc[m][n], 0, 0, 0);
    asm volatile("" ::: "memory");
    cur = (cur == 2) ? 0 : cur + 1;
  }

  int crow = row0 + wr + (lane >> 4) * 4;
  int ccol = col0 + wc + (lane & 15);
#pragma unroll
  for (int m = 0; m < 4; m++) {
#pragma unroll
    for (int n = 0; n < 4; n++) {
      int colg = ccol + n * 16;
      float bv = (colg < NPROJ) ? bias[colg] : 0.f;
#pragma unroll
      for (int j = 0; j < 4; j++) {
        int rowg = crow + m * 16 + j;
        float v = acc[m][n][j] + bv;
        if (colg < 1024) {
          zb[(size_t)rowg * 1024 + colg] = __float2bfloat16(v);
        } else if (colg < 2048) {
          // scan layout: [b][h][ps][t][w*16+pl]
          int cx = colg - 1024;
          int h = cx >> 6, p = cx & 63;
          int bb = rowg >> 10, t = (rowg >> 4) & 63, w = rowg & 15;
          size_t idx = ((((size_t)bb * 16 + h) * 4 + (p >> 4)) * 64 + t) * 256
                     + w * 16 + (p & 15);
          xsc[idx] = __float2bfloat16(v);
        } else if (colg < 2112) {
          aux[(size_t)rowg * 64 + (colg - 2048)] = v;
        }
      }
    }
  }
}

// ---------------- FF1 GEMM + SiLU gate (3-buf pipeline) -> bf16 -------------
__global__ __launch_bounds__(256) void ff1_fused_kernel(
    const bf16* __restrict__ A, const bf16* __restrict__ Bt,
    const float* __restrict__ bias, bf16* __restrict__ out, int K) {
  constexpr int BM = 128, ROWS = 384, ISS = 6;
  __shared__ __align__(16) bf16 sAB[3][ROWS][32];

  int wid = threadIdx.x >> 6, lane = threadIdx.x & 63;
  int row0 = blockIdx.y * BM, col0 = blockIdx.x * 128;
  int wr = (wid >> 1) * 64;
  int wc = (wid & 1) * 64;
  int lr = lane >> 2;
  int lc = (lane & 3) * 8;

  f32x4 acc1[4][4], acc2[4][4];
#pragma unroll
  for (int m = 0; m < 4; m++)
#pragma unroll
    for (int n = 0; n < 4; n++) {
      acc1[m][n] = (f32x4){0.f, 0.f, 0.f, 0.f};
      acc2[m][n] = (f32x4){0.f, 0.f, 0.f, 0.f};
    }

  auto stage = [&](int buf, int k0) {
#pragma unroll
    for (int i = 0; i < ISS; i++) {
      int rb = (wid * ISS + i) * 16;
      int r = rb + lr;
      const bf16* src;
      if (r < BM)       src = A  + (size_t)(row0 + r) * K + k0 + lc;
      else if (r < 256) src = Bt + (size_t)(col0 + (r - 128)) * K + k0 + lc;
      else              src = Bt + (size_t)(1024 + col0 + (r - 256)) * K + k0 + lc;
      __builtin_amdgcn_global_load_lds(
          (const __attribute__((address_space(1))) void*)src,
          (__attribute__((address_space(3))) void*)&sAB[buf][rb][0], 16, 0, 0);
    }
  };

  stage(0, 0);
  stage(1, 32);
  int cur = 0;
  for (int k0 = 0; k0 < K; k0 += 32) {
    if (k0 + 32 < K) vmwait<ISS>(); else vmwait<0>();
    __builtin_amdgcn_s_barrier();
    asm volatile("" ::: "memory");
    if (k0 + 64 < K) stage(cur == 0 ? 2 : cur - 1, k0 + 64);
    short8 a[4], b1[4], b2[4];
    int kk = (lane >> 4) * 8;
#pragma unroll
    for (int m = 0; m < 4; m++)
      a[m] = *(const short8*)&sAB[cur][wr + m * 16 + (lane & 15)][kk];
#pragma unroll
    for (int n = 0; n < 4; n++) {
      b1[n] = *(const short8*)&sAB[cur][128 + wc + n * 16 + (lane & 15)][kk];
      b2[n] = *(const short8*)&sAB[cur][256 + wc + n * 16 + (lane & 15)][kk];
    }
#pragma unroll
    for (int m = 0; m < 4; m++)
#pragma unroll
      for (int n = 0; n < 4; n++) {
        acc1[m][n] = __builtin_amdgcn_mfma_f32_16x16x32_bf16(a[m], b1[n], acc1[m][n], 0, 0, 0);
        acc2[m][n] = __builtin_amdgcn_mfma_f32_16x16x32_bf16(a[m], b2[n], acc2[m][n], 0, 0, 0);
      }
    asm volatile("" ::: "memory");
    cur = (cur == 2) ? 0 : cur + 1;
  }

  int crow = row0 + wr + (lane >> 4) * 4;
  int ccol = col0 + wc + (lane & 15);
#pragma unroll
  for (int m = 0; m < 4; m++) {
#pragma unroll
    for (int n = 0; n < 4; n++) {
      int colg = ccol + n * 16;
      float bv1 = bias[colg];
      float bv2 = bias[1024 + colg];
#pragma unroll
      for (int j = 0; j < 4; j++) {
        int rowg = crow + m * 16 + j;
        float f1 = acc1[m][n][j] + bv1;
        float g  = acc2[m][n][j] + bv2;
        float sg = g / (1.f + expf(-g));
        out[(size_t)rowg * 1024 + colg] = __float2bfloat16(f1 * sg);
      }
    }
  }
}

// ---------------- fused gate+RMS + out-proj (+bias +resid) -> xmid ----------
// A = bf16(yb*silu(zb)) reg-staged; norm_w pre-folded into Wt; rms scale
// applied to acc in epilogue (linearity). Proven 64x128 shape, 4 waves.
__global__ __launch_bounds__(256) void outproj_fused_kernel(
    const bf16* __restrict__ yb, const bf16* __restrict__ zb,
    const bf16* __restrict__ Wt, const float* __restrict__ out_b,
    const float* __restrict__ x, float* __restrict__ xmid) {
  constexpr int BM = 64, BN = 128, K = 1024;
  __shared__ __align__(16) bf16 sA[2][BM][32];
  __shared__ __align__(16) bf16 sB[2][BN][32];
  __shared__ float srow[BM];

  const int tid = threadIdx.x;
  const int wid = tid >> 6, lane = tid & 63;
  const int row0 = blockIdx.y * BM, col0 = blockIdx.x * BN;
  const int wc = wid * 32;            // NR=2 -> 32 cols per wave
  const int lr = lane >> 2, lc = (lane & 3) * 8;
  const int ar = tid >> 2, akc = (tid & 3) * 8;

  f32x4 acc[4][2];
#pragma unroll
  for (int m = 0; m < 4; m++)
#pragma unroll
    for (int n = 0; n < 2; n++) acc[m][n] = (f32x4){0.f, 0.f, 0.f, 0.f};
  float ssp = 0.f;

  uint4 yv, zv;
  auto stageB = [&](int buf, int k0) {
#pragma unroll
    for (int i = 0; i < 2; i++) {
      int rb = (wid * 2 + i) * 16;
      const bf16* src = Wt + (size_t)(col0 + rb + lr) * K + k0 + lc;
      __builtin_amdgcn_global_load_lds(
          (const __attribute__((address_space(1))) void*)src,
          (__attribute__((address_space(3))) void*)&sB[buf][rb][0], 16, 0, 0);
    }
  };
  auto loadA = [&](int k0) {
    yv = *(const uint4*)&yb[(size_t)(row0 + ar) * D_INNER + k0 + akc];
    zv = *(const uint4*)&zb[(size_t)(row0 + ar) * D_INNER + k0 + akc];
  };
  auto writeA = [&](int buf) {
    bf16 ya[8], za[8], tb[8];
    *(uint4*)ya = yv;
    *(uint4*)za = zv;
#pragma unroll
    for (int j = 0; j < 8; j++) {
      float z = __bfloat162float(za[j]);
      float t = __bfloat162float(ya[j]) * (z / (1.f + expf(-z)));
      ssp += t * t;
      tb[j] = __float2bfloat16(t);
    }
    *(uint4*)&sA[buf][ar][akc] = *(uint4*)tb;
  };

  stageB(0, 0);
  loadA(0);
  vmwait<0>();
  writeA(0);
  __syncthreads();

  int cur = 0;
  for (int k0 = 0; k0 < K; k0 += 32) {
    bool more = k0 + 32 < K;
    if (more) { stageB(cur ^ 1, k0 + 32); loadA(k0 + 32); }
    short8 a[4], b[2];
    int kk = (lane >> 4) * 8;
#pragma unroll
    for (int m = 0; m < 4; m++)
      a[m] = *(const short8*)&sA[cur][m * 16 + (lane & 15)][kk];
#pragma unroll
    for (int n = 0; n < 2; n++)
      b[n] = *(const short8*)&sB[cur][wc + n * 16 + (lane & 15)][kk];
#pragma unroll
    for (int m = 0; m < 4; m++)
#pragma unroll
      for (int n = 0; n < 2; n++)
        acc[m][n] = __builtin_amdgcn_mfma_f32_16x16x32_bf16(a[m], b[n], acc[m][n], 0, 0, 0);
    if (more) { vmwait<0>(); writeA(cur ^ 1); }
    __syncthreads();
    cur ^= 1;
  }

  // per-row rsqrt(mean(t^2)): reduce ssp across the 4 threads of each row
  ssp += __shfl_xor(ssp, 1, 4);
  ssp += __shfl_xor(ssp, 2, 4);
  if ((tid & 3) == 0) srow[ar] = rsqrtf(ssp * (1.f / 1024.f) + 1e-5f);
  __syncthreads();

  int ccol = col0 + wc + (lane & 15);
#pragma unroll
  for (int m = 0; m < 4; m++) {
#pragma unroll
    for (int j = 0; j < 4; j++) {
      int rl = (lane >> 4) * 4 + m * 16 + j;
      int rowg = row0 + rl;
      float sr = srow[rl];
#pragma unroll
      for (int n = 0; n < 2; n++) {
        int colg = ccol + n * 16;
        float v = acc[m][n][j] * sr + out_b[colg]
                + x[(size_t)rowg * D_MODEL + colg];
        xmid[(size_t)rowg * D_MODEL + colg] = v;
      }
    }
  }
}

// ---------------- tree scan (R11): coalesced x + T14 prefetch ---------------
__global__ __launch_bounds__(256) void tree_scan_kernel(
    const bf16* __restrict__ xsc, const float* __restrict__ aux,
    const int* __restrict__ parent,
    const float* __restrict__ A_log, const float* __restrict__ dt_bias,
    const float* __restrict__ Dp, bf16* __restrict__ y) {
  const int tid = threadIdx.x;
  const int ps = blockIdx.x & 3;
  const int h  = (blockIdx.x >> 2) & 15;
  const int b  = blockIdx.x >> 6;
  const int wid = tid >> 6;
  const int lane = tid & 63;
  const int w = lane >> 2;
  const int q = lane & 3;
  const int pl = wid * 4 + q;

  __shared__ __align__(16) u32   BCs[8][16][20];
  __shared__ __align__(16) float dAs[16][8];
  __shared__ __align__(16) float dtss[16][8];
  __shared__ __align__(16) int   pars[16][8];

  const float Ah  = -expf(A_log[h]);
  const float dtb = dt_bias[h];
  const float Dh  = Dp[h];
  const u16* xp = (const u16*)xsc
      + ((((size_t)b * 16 + h) * 4 + ps) * 64) * 256 + w * 16 + pl;
  const int ycol = (h << 6) + (ps << 4) + pl;

  float hst[16];
#pragma unroll
  for (int n = 0; n < 16; n++) hst[n] = 0.f;

  const int sp_t = tid >> 5, sp_w = (tid >> 1) & 15, sp_h = tid & 1;
  const int dt_t = tid >> 4, dt_w = tid & 15;

  u16 xpre[8];
  float4 bc0, bc1, bc2, bc3;
  float dtpre = 0.f;
  int papre = 0;

  auto issue = [&](int c) {
    const int t0 = c * 8;
#pragma unroll
    for (int tt = 0; tt < 8; tt++) xpre[tt] = xp[(size_t)(t0 + tt) * 256];
    size_t row = ((size_t)(b * NT + t0 + sp_t)) * NW + sp_w;
    const float* src = aux + row * 64 + sp_h * 16;
    bc0 = *(const float4*)&src[0];
    bc1 = *(const float4*)&src[4];
    bc2 = *(const float4*)&src[8];
    bc3 = *(const float4*)&src[12];
    if (tid < 128) {
      size_t r2 = ((size_t)(b * NT + t0 + dt_t)) * NW + dt_w;
      dtpre = aux[r2 * 64 + 32 + h];
      papre = parent[r2];
    }
  };

  issue(0);
  for (int c = 0; c < 8; c++) {
    const int t0 = c * 8;
    __syncthreads();
    float xv[8];
#pragma unroll
    for (int tt = 0; tt < 8; tt++) xv[tt] = ubits((u32)xpre[tt] << 16);
    if (tid < 128) {
      float dtr = dtpre + dtb;
      float dtv = (dtr > 20.f) ? dtr : log1pf(expf(dtr));
      dtss[dt_w][dt_t] = dtv;
      dAs[dt_w][dt_t]  = expf(dtv * Ah);
      pars[dt_w][dt_t] = papre;
    }
    {
      uint4 p0 = {pack_bf(bc0.x, bc0.y), pack_bf(bc0.z, bc0.w),
                  pack_bf(bc1.x, bc1.y), pack_bf(bc1.z, bc1.w)};
      uint4 p1 = {pack_bf(bc2.x, bc2.y), pack_bf(bc2.z, bc2.w),
                  pack_bf(bc3.x, bc3.y), pack_bf(bc3.z, bc3.w)};
      *(uint4*)&BCs[sp_t][sp_w][sp_h * 8]     = p0;
      *(uint4*)&BCs[sp_t][sp_w][sp_h * 8 + 4] = p1;
    }
    __syncthreads();
    float dAr[8], dtr8[8];
    int parr[8];
    *(float4*)&dAr[0]  = *(const float4*)&dAs[w][0];
    *(float4*)&dAr[4]  = *(const float4*)&dAs[w][4];
    *(float4*)&dtr8[0] = *(const float4*)&dtss[w][0];
    *(float4*)&dtr8[4] = *(const float4*)&dtss[w][4];
    *(int4*)&parr[0]   = *(const int4*)&pars[w][0];
    *(int4*)&parr[4]   = *(const int4*)&pars[w][4];
    if (c < 7) issue(c + 1);

#pragma unroll
    for (int tt = 0; tt < 8; tt++) {
      float dA  = dAr[tt];
      float dtx = dtr8[tt] * xv[tt];
      int   par = parr[tt];
      int gidx = (((par << 2) | q) << 2);
      u32 pk[8];
#pragma unroll
      for (int i = 0; i < 8; i++)
        pk[i] = (u32)__builtin_amdgcn_ds_bpermute(
            gidx, (int)pack_bf(hst[2 * i], hst[2 * i + 1]));
      uint4 bA = *(const uint4*)&BCs[tt][w][0];
      uint4 bB = *(const uint4*)&BCs[tt][w][4];
      uint4 cA = *(const uint4*)&BCs[tt][w][8];
      uint4 cB = *(const uint4*)&BCs[tt][w][12];
      u32 bwv[8] = {bA.x, bA.y, bA.z, bA.w, bB.x, bB.y, bB.z, bB.w};
      u32 cwv[8] = {cA.x, cA.y, cA.z, cA.w, cB.x, cB.y, cB.z, cB.w};
      float yv = 0.f;
#pragma unroll
      for (int i = 0; i < 8; i++) {
        u32 g = pk[i], bu = bwv[i], cu = cwv[i];
        float hp0 = ubits(g << 16);
        float hp1 = ubits(g & 0xffff0000u);
        float bl  = ubits(bu << 16), bh  = ubits(bu & 0xffff0000u);
        float cl  = ubits(cu << 16), ch  = ubits(cu & 0xffff0000u);
        float h0 = fmaf(dA, hp0, dtx * bl);
        float h1 = fmaf(dA, hp1, dtx * bh);
        hst[2 * i] = h0;
        hst[2 * i + 1] = h1;
        yv = fmaf(h0, cl, fmaf(h1, ch, yv));
      }
      size_t row = ((size_t)(b * NT + t0 + tt)) * NW + w;
      y[row * D_INNER + ycol] = __float2bfloat16(fmaf(Dh, xv[tt], yv));
    }
  }
}

extern "C" void kernel_launch(void* const* d_in, const int* in_sizes, int n_in,
                              void* d_out, int out_size, void* d_ws, size_t ws_size,
                              hipStream_t stream) {
  const float* x       = (const float*)d_in[0];
  const int*   parent  = (const int*)d_in[1];
  const float* ln1_w   = (const float*)d_in[2];
  const float* ln1_b   = (const float*)d_in[3];
  const float* in_w    = (const float*)d_in[4];
  const float* in_b    = (const float*)d_in[5];
  const float* A_log   = (const float*)d_in[6];
  const float* dt_bias = (const float*)d_in[7];
  const float* Dp      = (const float*)d_in[8];
  const float* norm_w  = (const float*)d_in[9];
  const float* out_w   = (const float*)d_in[10];
  const float* out_b   = (const float*)d_in[11];
  const float* ln2_w   = (const float*)d_in[12];
  const float* ln2_b   = (const float*)d_in[13];
  const float* ff1_w   = (const float*)d_in[14];
  const float* ff1_b   = (const float*)d_in[15];
  const float* ff2_w   = (const float*)d_in[16];
  const float* ff2_b   = (const float*)d_in[17];
  float* outp = (float*)d_out;

  char* wp = (char*)d_ws;
  bf16* xnb    = (bf16*)wp;  wp += (size_t)MROWS * D_MODEL * 2;
  bf16* in_wt  = (bf16*)wp;  wp += (size_t)2176 * D_MODEL * 2;
  bf16* out_wt = (bf16*)wp;  wp += (size_t)D_MODEL * D_INNER * 2;
  bf16* ff1_wt = (bf16*)wp;  wp += (size_t)2048 * D_MODEL * 2;
  bf16* ff2_wt = (bf16*)wp;  wp += (size_t)D_MODEL * D_INNER * 2;
  bf16* zb     = (bf16*)wp;  wp += (size_t)MROWS * D_INNER * 2;
  bf16* xsc    = (bf16*)wp;  wp += (size_t)MROWS * D_INNER * 2;
  float* aux   = (float*)wp; wp += (size_t)MROWS * 64 * 4;
  bf16* yb     = (bf16*)wp;  wp += (size_t)MROWS * D_INNER * 2;
  float* xmid  = outp;  // d_out doubles as xmid

  dim3 blk(256);
  // 0) all weight converts in one dispatch (norm_w folded into out_wt)
  wconv_all_kernel<<<3136, blk, 0, stream>>>(
      in_w, in_wt, out_w, out_wt, norm_w, ff1_w, ff1_wt, ff2_w, ff2_wt);
  // 1) LN1 -> bf16
  ln512_bf16_kernel<<<MROWS, blk, 0, stream>>>(x, ln1_w, ln1_b, xnb);
  // 2) in-proj GEMM -> zb + xsc (scan layout) + aux
  inproj_gemm_kernel<<<dim3(2176 / 128, MROWS / 128), blk, 0, stream>>>(
      xnb, in_wt, in_b, zb, xsc, aux, D_MODEL);
  // 3) tree scan -> yb (bf16)
  tree_scan_kernel<<<NB * NHEAD * 4, blk, 0, stream>>>(xsc, aux, parent,
                                                       A_log, dt_bias, Dp, yb);
  // 4) fused gate+RMS + out-proj + resid(x) -> xmid (=d_out)
  outproj_fused_kernel<<<dim3(D_MODEL / 128, MROWS / 64), blk, 0, stream>>>(
      yb, zb, out_wt, out_b, x, xmid);
  // 5) LN2 -> xnb
  ln512_bf16_kernel<<<MROWS, blk, 0, stream>>>(xmid, ln2_w, ln2_b, xnb);
  // 6) FF1 GEMM + SiLU gate fused -> yb (reuse)
  ff1_fused_kernel<<<dim3(8, MROWS / 128), blk, 0, stream>>>(
      xnb, ff1_wt, ff1_b, yb, D_MODEL);
  // 7) FF2 GEMM + resid(xmid) -> d_out
  mfma_gemm_kernel<64, 128, 4, 4, 2><<<dim3(D_MODEL / 128, MROWS / 64), blk, 0, stream>>>(
      yb, ff2_wt, ff2_b, D_MODEL, xmid, outp, D_MODEL, D_INNER);
}

// Round 14
// 196.793 us; speedup vs baseline: 1.0986x; 1.0986x over previous
//
#include <hip/hip_runtime.h>
#include <hip/hip_bf16.h>
#include <cmath>

#define D_MODEL 512
#define D_INNER 1024
#define NHEAD 16
#define HDIM 64
#define NSTATE 16
#define NB 8
#define NT 64
#define NW 16
#define MROWS 8192      // NB*NT*NW
#define NPROJ 2096

typedef __attribute__((ext_vector_type(8))) short short8;
typedef __attribute__((ext_vector_type(4))) float f32x4;
typedef __hip_bfloat16 bf16;
typedef unsigned int u32;
typedef unsigned short u16;

__device__ __forceinline__ u32 fbits(float f) { return __float_as_uint(f); }
__device__ __forceinline__ float ubits(u32 u) { return __uint_as_float(u); }
__device__ __forceinline__ u32 pack_bf(float a, float b) {
  return (fbits(b) & 0xffff0000u) | (fbits(a) >> 16);
}

// counted vmcnt wait (literal immediates; "memory" clobber = compiler fence)
template<int N> __device__ __forceinline__ void vmwait() {
  if constexpr (N == 0)      asm volatile("s_waitcnt vmcnt(0)" ::: "memory");
  else if constexpr (N == 2) asm volatile("s_waitcnt vmcnt(2)" ::: "memory");
  else if constexpr (N == 3) asm volatile("s_waitcnt vmcnt(3)" ::: "memory");
  else if constexpr (N == 4) asm volatile("s_waitcnt vmcnt(4)" ::: "memory");
  else if constexpr (N == 6) asm volatile("s_waitcnt vmcnt(6)" ::: "memory");
  else if constexpr (N == 8) asm volatile("s_waitcnt vmcnt(8)" ::: "memory");
  else static_assert(N == 0, "unsupported vmcnt");
}

// T1: XCD-aware tile remap (requires nwg % 8 == 0; all our grids qualify).
// XCD k (ids ≡ k mod 8) computes a contiguous run of tiles -> row-panel
// locality within one XCD's L2.
__device__ __forceinline__ void xcd_tile(int& bx, int& by) {
  int gx = gridDim.x;
  int nwg = gx * gridDim.y;
  int id = blockIdx.y * gx + blockIdx.x;
  int tile = (id & 7) * (nwg >> 3) + (id >> 3);
  bx = tile % gx;
  by = tile / gx;
}

// ---------------- block-wide sum reduction (256 threads = 4 waves) ----------
__device__ __forceinline__ float block_sum(float v, float* sbuf) {
#pragma unroll
  for (int o = 32; o > 0; o >>= 1) v += __shfl_down(v, o, 64);
  int lane = threadIdx.x & 63, wid = threadIdx.x >> 6;
  if (lane == 0) sbuf[wid] = v;
  __syncthreads();
  if (threadIdx.x == 0) {
    float t = 0.f;
    for (int i = 0; i < 4; i++) t += sbuf[i];
    sbuf[0] = t;
  }
  __syncthreads();
  return sbuf[0];
}

// ---------------- LayerNorm over 512, bf16 out ------------------------------
__global__ __launch_bounds__(256) void ln512_bf16_kernel(
    const float* __restrict__ x, const float* __restrict__ w,
    const float* __restrict__ b, bf16* __restrict__ out) {
  __shared__ float s1[8], s2[8];
  int row = blockIdx.x;
  const float* xr = x + (size_t)row * D_MODEL;
  bf16* outr = out + (size_t)row * D_MODEL;
  int c0 = threadIdx.x, c1 = threadIdx.x + 256;
  float v0 = xr[c0], v1 = xr[c1];
  float s  = block_sum(v0 + v1, s1);
  float ss = block_sum(v0 * v0 + v1 * v1, s2);
  float mean = s * (1.f / 512.f);
  float var  = ss * (1.f / 512.f) - mean * mean;
  float inv  = rsqrtf(var + 1e-5f);
  outr[c0] = __float2bfloat16((v0 - mean) * inv * w[c0] + b[c0]);
  outr[c1] = __float2bfloat16((v1 - mean) * inv * w[c1] + b[c1]);
}

// ---------------- merged weight convert+transpose (4 configs in 1 grid) -----
__global__ __launch_bounds__(256) void wconv_all_kernel(
    const float* __restrict__ in_w, bf16* __restrict__ in_wt,
    const float* __restrict__ out_w, bf16* __restrict__ out_wt,
    const float* __restrict__ ff1_w, bf16* __restrict__ ff1_wt,
    const float* __restrict__ ff2_w, bf16* __restrict__ ff2_wt) {
  __shared__ float tile[32][33];
  int id = blockIdx.x;
  const float* w; bf16* wt;
  int K, N, Npad, bx, by;
  if (id < 1088)      { w = in_w;  wt = in_wt;  K = 512;  N = NPROJ; Npad = 2176; bx = id % 68;  by = id / 68; }
  else if (id < 1600) { int j = id - 1088; w = out_w; wt = out_wt; K = 1024; N = 512;  Npad = 512;  bx = j % 16; by = j / 16; }
  else if (id < 2624) { int j = id - 1600; w = ff1_w; wt = ff1_wt; K = 512;  N = 2048; Npad = 2048; bx = j % 64; by = j / 64; }
  else                { int j = id - 2624; w = ff2_w; wt = ff2_wt; K = 1024; N = 512;  Npad = 512;  bx = j % 16; by = j / 16; }
  int n0 = bx * 32, k0 = by * 32;
  int tx = threadIdx.x & 31, ty = threadIdx.x >> 5;  // 32 x 8
#pragma unroll
  for (int i = 0; i < 4; i++) {
    int k = k0 + ty + i * 8, n = n0 + tx;
    tile[ty + i * 8][tx] = (k < K && n < N) ? w[(size_t)k * N + n] : 0.f;
  }
  __syncthreads();
#pragma unroll
  for (int i = 0; i < 4; i++) {
    int n = n0 + ty + i * 8, k = k0 + tx;
    if (n < Npad && k < K)
      wt[(size_t)n * K + k] = __float2bfloat16(tile[tx][ty + i * 8]);
  }
}

// ---------------- fp32-out MFMA GEMM, 3-buffer counted-vmcnt + T1 swizzle ---
template<int BM, int BN, int WN, int MR, int NR>
__global__ __launch_bounds__(256) void mfma_gemm_kernel(
    const bf16* __restrict__ A, const bf16* __restrict__ Bt,
    const float* __restrict__ bias, int nbias,
    const float* __restrict__ resid,
    float* __restrict__ C, int ldc, int K) {
  constexpr int ROWS = BM + BN;
  constexpr int ISS  = ROWS / 64;
  __shared__ __align__(16) bf16 sAB[3][ROWS][32];

  int wid = threadIdx.x >> 6, lane = threadIdx.x & 63;
  int bx, by;
  xcd_tile(bx, by);
  int row0 = by * BM, col0 = bx * BN;
  int wr = (wid / WN) * (MR * 16);
  int wc = (wid % WN) * (NR * 16);
  int lr = lane >> 2;
  int lc = (lane & 3) * 8;

  f32x4 acc[MR][NR];
#pragma unroll
  for (int m = 0; m < MR; m++)
#pragma unroll
    for (int n = 0; n < NR; n++) acc[m][n] = (f32x4){0.f, 0.f, 0.f, 0.f};

  auto stage = [&](int buf, int k0) {
#pragma unroll
    for (int i = 0; i < ISS; i++) {
      int rb = (wid * ISS + i) * 16;
      int r = rb + lr;
      const bf16* src = (r < BM)
          ? A  + (size_t)(row0 + r) * K + k0 + lc
          : Bt + (size_t)(col0 + (r - BM)) * K + k0 + lc;
      __builtin_amdgcn_global_load_lds(
          (const __attribute__((address_space(1))) void*)src,
          (__attribute__((address_space(3))) void*)&sAB[buf][rb][0], 16, 0, 0);
    }
  };

  stage(0, 0);
  stage(1, 32);
  int cur = 0;
  for (int k0 = 0; k0 < K; k0 += 32) {
    if (k0 + 32 < K) vmwait<ISS>(); else vmwait<0>();
    __builtin_amdgcn_s_barrier();
    asm volatile("" ::: "memory");
    if (k0 + 64 < K) stage(cur == 0 ? 2 : cur - 1, k0 + 64);
    short8 a[MR], b[NR];
    int kk = (lane >> 4) * 8;
#pragma unroll
    for (int m = 0; m < MR; m++)
      a[m] = *(const short8*)&sAB[cur][wr + m * 16 + (lane & 15)][kk];
#pragma unroll
    for (int n = 0; n < NR; n++)
      b[n] = *(const short8*)&sAB[cur][BM + wc + n * 16 + (lane & 15)][kk];
#pragma unroll
    for (int m = 0; m < MR; m++)
#pragma unroll
      for (int n = 0; n < NR; n++)
        acc[m][n] = __builtin_amdgcn_mfma_f32_16x16x32_bf16(a[m], b[n], acc[m][n], 0, 0, 0);
    asm volatile("" ::: "memory");
    cur = (cur == 2) ? 0 : cur + 1;
  }

  int crow = row0 + wr + (lane >> 4) * 4;
  int ccol = col0 + wc + (lane & 15);
#pragma unroll
  for (int m = 0; m < MR; m++) {
#pragma unroll
    for (int n = 0; n < NR; n++) {
      int colg = ccol + n * 16;
      float bv = bias ? ((colg < nbias) ? bias[colg] : 0.f) : 0.f;
#pragma unroll
      for (int j = 0; j < 4; j++) {
        int rowg = crow + m * 16 + j;
        float v = acc[m][n][j] + bv;
        if (resid) v += resid[(size_t)rowg * ldc + colg];
        C[(size_t)rowg * ldc + colg] = v;
      }
    }
  }
}

// ---------------- in-proj GEMM (3-buf + T1): z->zb, x->xsc, aux -------------
__global__ __launch_bounds__(256) void inproj_gemm_kernel(
    const bf16* __restrict__ A, const bf16* __restrict__ Bt,
    const float* __restrict__ bias,
    bf16* __restrict__ zb, bf16* __restrict__ xsc,
    float* __restrict__ aux, int K) {
  constexpr int BM = 128, ROWS = 256, ISS = 4;
  __shared__ __align__(16) bf16 sAB[3][ROWS][32];

  int wid = threadIdx.x >> 6, lane = threadIdx.x & 63;
  int bx, by;
  xcd_tile(bx, by);
  int row0 = by * BM, col0 = bx * 128;
  int wr = (wid >> 1) * 64;
  int wc = (wid & 1) * 64;
  int lr = lane >> 2;
  int lc = (lane & 3) * 8;

  f32x4 acc[4][4];
#pragma unroll
  for (int m = 0; m < 4; m++)
#pragma unroll
    for (int n = 0; n < 4; n++) acc[m][n] = (f32x4){0.f, 0.f, 0.f, 0.f};

  auto stage = [&](int buf, int k0) {
#pragma unroll
    for (int i = 0; i < ISS; i++) {
      int rb = (wid * ISS + i) * 16;
      int r = rb + lr;
      const bf16* src = (r < BM)
          ? A  + (size_t)(row0 + r) * K + k0 + lc
          : Bt + (size_t)(col0 + (r - BM)) * K + k0 + lc;
      __builtin_amdgcn_global_load_lds(
          (const __attribute__((address_space(1))) void*)src,
          (__attribute__((address_space(3))) void*)&sAB[buf][rb][0], 16, 0, 0);
    }
  };

  stage(0, 0);
  stage(1, 32);
  int cur = 0;
  for (int k0 = 0; k0 < K; k0 += 32) {
    if (k0 + 32 < K) vmwait<ISS>(); else vmwait<0>();
    __builtin_amdgcn_s_barrier();
    asm volatile("" ::: "memory");
    if (k0 + 64 < K) stage(cur == 0 ? 2 : cur - 1, k0 + 64);
    short8 a[4], b[4];
    int kk = (lane >> 4) * 8;
#pragma unroll
    for (int m = 0; m < 4; m++)
      a[m] = *(const short8*)&sAB[cur][wr + m * 16 + (lane & 15)][kk];
#pragma unroll
    for (int n = 0; n < 4; n++)
      b[n] = *(const short8*)&sAB[cur][BM + wc + n * 16 + (lane & 15)][kk];
#pragma unroll
    for (int m = 0; m < 4; m++)
#pragma unroll
      for (int n = 0; n < 4; n++)
        acc[m][n] = __builtin_amdgcn_mfma_f32_16x16x32_bf16(a[m], b[n], acc[m][n], 0, 0, 0);
    asm volatile("" ::: "memory");
    cur = (cur == 2) ? 0 : cur + 1;
  }

  int crow = row0 + wr + (lane >> 4) * 4;
  int ccol = col0 + wc + (lane & 15);
#pragma unroll
  for (int m = 0; m < 4; m++) {
#pragma unroll
    for (int n = 0; n < 4; n++) {
      int colg = ccol + n * 16;
      float bv = (colg < NPROJ) ? bias[colg] : 0.f;
#pragma unroll
      for (int j = 0; j < 4; j++) {
        int rowg = crow + m * 16 + j;
        float v = acc[m][n][j] + bv;
        if (colg < 1024) {
          zb[(size_t)rowg * 1024 + colg] = __float2bfloat16(v);
        } else if (colg < 2048) {
          // scan layout: [b][h][ps][t][w*16+pl]
          int cx = colg - 1024;
          int h = cx >> 6, p = cx & 63;
          int bb = rowg >> 10, t = (rowg >> 4) & 63, w = rowg & 15;
          size_t idx = ((((size_t)bb * 16 + h) * 4 + (p >> 4)) * 64 + t) * 256
                     + w * 16 + (p & 15);
          xsc[idx] = __float2bfloat16(v);
        } else if (colg < 2112) {
          aux[(size_t)rowg * 64 + (colg - 2048)] = v;
        }
      }
    }
  }
}

// ---------------- FF1 GEMM + SiLU gate (3-buf + T1) -> bf16 -----------------
__global__ __launch_bounds__(256) void ff1_fused_kernel(
    const bf16* __restrict__ A, const bf16* __restrict__ Bt,
    const float* __restrict__ bias, bf16* __restrict__ out, int K) {
  constexpr int BM = 128, ROWS = 384, ISS = 6;
  __shared__ __align__(16) bf16 sAB[3][ROWS][32];

  int wid = threadIdx.x >> 6, lane = threadIdx.x & 63;
  int bx, by;
  xcd_tile(bx, by);
  int row0 = by * BM, col0 = bx * 128;
  int wr = (wid >> 1) * 64;
  int wc = (wid & 1) * 64;
  int lr = lane >> 2;
  int lc = (lane & 3) * 8;

  f32x4 acc1[4][4], acc2[4][4];
#pragma unroll
  for (int m = 0; m < 4; m++)
#pragma unroll
    for (int n = 0; n < 4; n++) {
      acc1[m][n] = (f32x4){0.f, 0.f, 0.f, 0.f};
      acc2[m][n] = (f32x4){0.f, 0.f, 0.f, 0.f};
    }

  auto stage = [&](int buf, int k0) {
#pragma unroll
    for (int i = 0; i < ISS; i++) {
      int rb = (wid * ISS + i) * 16;
      int r = rb + lr;
      const bf16* src;
      if (r < BM)       src = A  + (size_t)(row0 + r) * K + k0 + lc;
      else if (r < 256) src = Bt + (size_t)(col0 + (r - 128)) * K + k0 + lc;
      else              src = Bt + (size_t)(1024 + col0 + (r - 256)) * K + k0 + lc;
      __builtin_amdgcn_global_load_lds(
          (const __attribute__((address_space(1))) void*)src,
          (__attribute__((address_space(3))) void*)&sAB[buf][rb][0], 16, 0, 0);
    }
  };

  stage(0, 0);
  stage(1, 32);
  int cur = 0;
  for (int k0 = 0; k0 < K; k0 += 32) {
    if (k0 + 32 < K) vmwait<ISS>(); else vmwait<0>();
    __builtin_amdgcn_s_barrier();
    asm volatile("" ::: "memory");
    if (k0 + 64 < K) stage(cur == 0 ? 2 : cur - 1, k0 + 64);
    short8 a[4], b1[4], b2[4];
    int kk = (lane >> 4) * 8;
#pragma unroll
    for (int m = 0; m < 4; m++)
      a[m] = *(const short8*)&sAB[cur][wr + m * 16 + (lane & 15)][kk];
#pragma unroll
    for (int n = 0; n < 4; n++) {
      b1[n] = *(const short8*)&sAB[cur][128 + wc + n * 16 + (lane & 15)][kk];
      b2[n] = *(const short8*)&sAB[cur][256 + wc + n * 16 + (lane & 15)][kk];
    }
#pragma unroll
    for (int m = 0; m < 4; m++)
#pragma unroll
      for (int n = 0; n < 4; n++) {
        acc1[m][n] = __builtin_amdgcn_mfma_f32_16x16x32_bf16(a[m], b1[n], acc1[m][n], 0, 0, 0);
        acc2[m][n] = __builtin_amdgcn_mfma_f32_16x16x32_bf16(a[m], b2[n], acc2[m][n], 0, 0, 0);
      }
    asm volatile("" ::: "memory");
    cur = (cur == 2) ? 0 : cur + 1;
  }

  int crow = row0 + wr + (lane >> 4) * 4;
  int ccol = col0 + wc + (lane & 15);
#pragma unroll
  for (int m = 0; m < 4; m++) {
#pragma unroll
    for (int n = 0; n < 4; n++) {
      int colg = ccol + n * 16;
      float bv1 = bias[colg];
      float bv2 = bias[1024 + colg];
#pragma unroll
      for (int j = 0; j < 4; j++) {
        int rowg = crow + m * 16 + j;
        float f1 = acc1[m][n][j] + bv1;
        float g  = acc2[m][n][j] + bv2;
        float sg = g / (1.f + expf(-g));
        out[(size_t)rowg * 1024 + colg] = __float2bfloat16(f1 * sg);
      }
    }
  }
}

// ---------------- tree scan (R11): coalesced x + T14 prefetch ---------------
__global__ __launch_bounds__(256) void tree_scan_kernel(
    const bf16* __restrict__ xsc, const float* __restrict__ aux,
    const int* __restrict__ parent,
    const float* __restrict__ A_log, const float* __restrict__ dt_bias,
    const float* __restrict__ Dp, bf16* __restrict__ y) {
  const int tid = threadIdx.x;
  const int ps = blockIdx.x & 3;
  const int h  = (blockIdx.x >> 2) & 15;
  const int b  = blockIdx.x >> 6;
  const int wid = tid >> 6;
  const int lane = tid & 63;
  const int w = lane >> 2;
  const int q = lane & 3;
  const int pl = wid * 4 + q;

  __shared__ __align__(16) u32   BCs[8][16][20];
  __shared__ __align__(16) float dAs[16][8];
  __shared__ __align__(16) float dtss[16][8];
  __shared__ __align__(16) int   pars[16][8];

  const float Ah  = -expf(A_log[h]);
  const float dtb = dt_bias[h];
  const float Dh  = Dp[h];
  const u16* xp = (const u16*)xsc
      + ((((size_t)b * 16 + h) * 4 + ps) * 64) * 256 + w * 16 + pl;
  const int ycol = (h << 6) + (ps << 4) + pl;

  float hst[16];
#pragma unroll
  for (int n = 0; n < 16; n++) hst[n] = 0.f;

  const int sp_t = tid >> 5, sp_w = (tid >> 1) & 15, sp_h = tid & 1;
  const int dt_t = tid >> 4, dt_w = tid & 15;

  u16 xpre[8];
  float4 bc0, bc1, bc2, bc3;
  float dtpre = 0.f;
  int papre = 0;

  auto issue = [&](int c) {
    const int t0 = c * 8;
#pragma unroll
    for (int tt = 0; tt < 8; tt++) xpre[tt] = xp[(size_t)(t0 + tt) * 256];
    size_t row = ((size_t)(b * NT + t0 + sp_t)) * NW + sp_w;
    const float* src = aux + row * 64 + sp_h * 16;
    bc0 = *(const float4*)&src[0];
    bc1 = *(const float4*)&src[4];
    bc2 = *(const float4*)&src[8];
    bc3 = *(const float4*)&src[12];
    if (tid < 128) {
      size_t r2 = ((size_t)(b * NT + t0 + dt_t)) * NW + dt_w;
      dtpre = aux[r2 * 64 + 32 + h];
      papre = parent[r2];
    }
  };

  issue(0);
  for (int c = 0; c < 8; c++) {
    const int t0 = c * 8;
    __syncthreads();
    float xv[8];
#pragma unroll
    for (int tt = 0; tt < 8; tt++) xv[tt] = ubits((u32)xpre[tt] << 16);
    if (tid < 128) {
      float dtr = dtpre + dtb;
      float dtv = (dtr > 20.f) ? dtr : log1pf(expf(dtr));
      dtss[dt_w][dt_t] = dtv;
      dAs[dt_w][dt_t]  = expf(dtv * Ah);
      pars[dt_w][dt_t] = papre;
    }
    {
      uint4 p0 = {pack_bf(bc0.x, bc0.y), pack_bf(bc0.z, bc0.w),
                  pack_bf(bc1.x, bc1.y), pack_bf(bc1.z, bc1.w)};
      uint4 p1 = {pack_bf(bc2.x, bc2.y), pack_bf(bc2.z, bc2.w),
                  pack_bf(bc3.x, bc3.y), pack_bf(bc3.z, bc3.w)};
      *(uint4*)&BCs[sp_t][sp_w][sp_h * 8]     = p0;
      *(uint4*)&BCs[sp_t][sp_w][sp_h * 8 + 4] = p1;
    }
    __syncthreads();
    float dAr[8], dtr8[8];
    int parr[8];
    *(float4*)&dAr[0]  = *(const float4*)&dAs[w][0];
    *(float4*)&dAr[4]  = *(const float4*)&dAs[w][4];
    *(float4*)&dtr8[0] = *(const float4*)&dtss[w][0];
    *(float4*)&dtr8[4] = *(const float4*)&dtss[w][4];
    *(int4*)&parr[0]   = *(const int4*)&pars[w][0];
    *(int4*)&parr[4]   = *(const int4*)&pars[w][4];
    if (c < 7) issue(c + 1);

#pragma unroll
    for (int tt = 0; tt < 8; tt++) {
      float dA  = dAr[tt];
      float dtx = dtr8[tt] * xv[tt];
      int   par = parr[tt];
      int gidx = (((par << 2) | q) << 2);
      u32 pk[8];
#pragma unroll
      for (int i = 0; i < 8; i++)
        pk[i] = (u32)__builtin_amdgcn_ds_bpermute(
            gidx, (int)pack_bf(hst[2 * i], hst[2 * i + 1]));
      uint4 bA = *(const uint4*)&BCs[tt][w][0];
      uint4 bB = *(const uint4*)&BCs[tt][w][4];
      uint4 cA = *(const uint4*)&BCs[tt][w][8];
      uint4 cB = *(const uint4*)&BCs[tt][w][12];
      u32 bwv[8] = {bA.x, bA.y, bA.z, bA.w, bB.x, bB.y, bB.z, bB.w};
      u32 cwv[8] = {cA.x, cA.y, cA.z, cA.w, cB.x, cB.y, cB.z, cB.w};
      float yv = 0.f;
#pragma unroll
      for (int i = 0; i < 8; i++) {
        u32 g = pk[i], bu = bwv[i], cu = cwv[i];
        float hp0 = ubits(g << 16);
        float hp1 = ubits(g & 0xffff0000u);
        float bl  = ubits(bu << 16), bh  = ubits(bu & 0xffff0000u);
        float cl  = ubits(cu << 16), ch  = ubits(cu & 0xffff0000u);
        float h0 = fmaf(dA, hp0, dtx * bl);
        float h1 = fmaf(dA, hp1, dtx * bh);
        hst[2 * i] = h0;
        hst[2 * i + 1] = h1;
        yv = fmaf(h0, cl, fmaf(h1, ch, yv));
      }
      size_t row = ((size_t)(b * NT + t0 + tt)) * NW + w;
      y[row * D_INNER + ycol] = __float2bfloat16(fmaf(Dh, xv[tt], yv));
    }
  }
}

// ---------------- gated RMSNorm (bf16 in/out, compact z) --------------------
__global__ __launch_bounds__(256) void gate_rms_kernel(
    const bf16* __restrict__ yin, const bf16* __restrict__ zb,
    const float* __restrict__ norm_w, bf16* __restrict__ out) {
  __shared__ float sbuf[8];
  int row = blockIdx.x;
  const bf16* yr = yin + (size_t)row * D_INNER;
  const bf16* zr = zb + (size_t)row * D_INNER;
  int c = threadIdx.x * 4;
  bf16 y4[4], z4[4];
  *(uint2*)y4 = *(const uint2*)&yr[c];
  *(uint2*)z4 = *(const uint2*)&zr[c];
  float gv[4];
  float ss = 0.f;
#pragma unroll
  for (int j = 0; j < 4; j++) {
    float z = __bfloat162float(z4[j]);
    float t = __bfloat162float(y4[j]) * (z / (1.f + expf(-z)));
    gv[j] = t;
    ss += t * t;
  }
  ss = block_sum(ss, sbuf);
  float scale = rsqrtf(ss * (1.f / 1024.f) + 1e-5f);
  bf16 o4[4];
#pragma unroll
  for (int j = 0; j < 4; j++) o4[j] = __float2bfloat16(gv[j] * scale * norm_w[c + j]);
  *(uint2*)&out[(size_t)row * D_INNER + c] = *(uint2*)o4;
}

extern "C" void kernel_launch(void* const* d_in, const int* in_sizes, int n_in,
                              void* d_out, int out_size, void* d_ws, size_t ws_size,
                              hipStream_t stream) {
  const float* x       = (const float*)d_in[0];
  const int*   parent  = (const int*)d_in[1];
  const float* ln1_w   = (const float*)d_in[2];
  const float* ln1_b   = (const float*)d_in[3];
  const float* in_w    = (const float*)d_in[4];
  const float* in_b    = (const float*)d_in[5];
  const float* A_log   = (const float*)d_in[6];
  const float* dt_bias = (const float*)d_in[7];
  const float* Dp      = (const float*)d_in[8];
  const float* norm_w  = (const float*)d_in[9];
  const float* out_w   = (const float*)d_in[10];
  const float* out_b   = (const float*)d_in[11];
  const float* ln2_w   = (const float*)d_in[12];
  const float* ln2_b   = (const float*)d_in[13];
  const float* ff1_w   = (const float*)d_in[14];
  const float* ff1_b   = (const float*)d_in[15];
  const float* ff2_w   = (const float*)d_in[16];
  const float* ff2_b   = (const float*)d_in[17];
  float* outp = (float*)d_out;

  char* wp = (char*)d_ws;
  bf16* xnb    = (bf16*)wp;  wp += (size_t)MROWS * D_MODEL * 2;
  bf16* in_wt  = (bf16*)wp;  wp += (size_t)2176 * D_MODEL * 2;
  bf16* out_wt = (bf16*)wp;  wp += (size_t)D_MODEL * D_INNER * 2;
  bf16* ff1_wt = (bf16*)wp;  wp += (size_t)2048 * D_MODEL * 2;
  bf16* ff2_wt = (bf16*)wp;  wp += (size_t)D_MODEL * D_INNER * 2;
  bf16* zb     = (bf16*)wp;  wp += (size_t)MROWS * D_INNER * 2;
  bf16* xsc    = (bf16*)wp;  wp += (size_t)MROWS * D_INNER * 2;
  float* aux   = (float*)wp; wp += (size_t)MROWS * 64 * 4;
  bf16* yb     = (bf16*)wp;  wp += (size_t)MROWS * D_INNER * 2;
  bf16* ygb    = (bf16*)wp;  wp += (size_t)MROWS * D_INNER * 2;
  float* xmid  = outp;  // d_out doubles as xmid

  dim3 blk(256);
  // 0) all weight converts in one dispatch
  wconv_all_kernel<<<3136, blk, 0, stream>>>(
      in_w, in_wt, out_w, out_wt, ff1_w, ff1_wt, ff2_w, ff2_wt);
  // 1) LN1 -> bf16
  ln512_bf16_kernel<<<MROWS, blk, 0, stream>>>(x, ln1_w, ln1_b, xnb);
  // 2) in-proj GEMM -> zb + xsc (scan layout) + aux
  inproj_gemm_kernel<<<dim3(2176 / 128, MROWS / 128), blk, 0, stream>>>(
      xnb, in_wt, in_b, zb, xsc, aux, D_MODEL);
  // 3) tree scan -> yb (bf16)
  tree_scan_kernel<<<NB * NHEAD * 4, blk, 0, stream>>>(xsc, aux, parent,
                                                       A_log, dt_bias, Dp, yb);
  // 4) gated RMSNorm -> ygb (bf16)
  gate_rms_kernel<<<MROWS, blk, 0, stream>>>(yb, zb, norm_w, ygb);
  // 5) out-proj GEMM + resid(x) -> xmid (fp32)
  mfma_gemm_kernel<64, 128, 4, 4, 2><<<dim3(D_MODEL / 128, MROWS / 64), blk, 0, stream>>>(
      ygb, out_wt, out_b, D_MODEL, x, xmid, D_MODEL, D_INNER);
  // 6) LN2 -> xnb
  ln512_bf16_kernel<<<MROWS, blk, 0, stream>>>(xmid, ln2_w, ln2_b, xnb);
  // 7) FF1 GEMM + SiLU gate fused -> yb (reuse)
  ff1_fused_kernel<<<dim3(8, MROWS / 128), blk, 0, stream>>>(
      xnb, ff1_wt, ff1_b, yb, D_MODEL);
  // 8) FF2 GEMM + resid(xmid) -> d_out
  mfma_gemm_kernel<64, 128, 4, 4, 2><<<dim3(D_MODEL / 128, MROWS / 64), blk, 0, stream>>>(
      yb, ff2_wt, ff2_b, D_MODEL, xmid, outp, D_MODEL, D_INNER);
}

// Round 15
// 193.436 us; speedup vs baseline: 1.1176x; 1.0174x over previous
//
#include <hip/hip_runtime.h>
#include <hip/hip_bf16.h>
#include <cmath>

#define D_MODEL 512
#define D_INNER 1024
#define NHEAD 16
#define HDIM 64
#define NSTATE 16
#define NB 8
#define NT 64
#define NW 16
#define MROWS 8192      // NB*NT*NW
#define NPROJ 2096

typedef __attribute__((ext_vector_type(8))) short short8;
typedef __attribute__((ext_vector_type(4))) float f32x4;
typedef __hip_bfloat16 bf16;
typedef unsigned int u32;
typedef unsigned short u16;

__device__ __forceinline__ u32 fbits(float f) { return __float_as_uint(f); }
__device__ __forceinline__ float ubits(u32 u) { return __uint_as_float(u); }
__device__ __forceinline__ u32 pack_bf(float a, float b) {
  return (fbits(b) & 0xffff0000u) | (fbits(a) >> 16);
}

// counted vmcnt wait (literal immediates; "memory" clobber = compiler fence)
template<int N> __device__ __forceinline__ void vmwait() {
  if constexpr (N == 0)      asm volatile("s_waitcnt vmcnt(0)" ::: "memory");
  else if constexpr (N == 2) asm volatile("s_waitcnt vmcnt(2)" ::: "memory");
  else if constexpr (N == 3) asm volatile("s_waitcnt vmcnt(3)" ::: "memory");
  else if constexpr (N == 4) asm volatile("s_waitcnt vmcnt(4)" ::: "memory");
  else if constexpr (N == 6) asm volatile("s_waitcnt vmcnt(6)" ::: "memory");
  else if constexpr (N == 8) asm volatile("s_waitcnt vmcnt(8)" ::: "memory");
  else static_assert(N == 0, "unsupported vmcnt");
}

// T1: XCD-aware tile remap (requires nwg % 8 == 0; all our grids qualify).
__device__ __forceinline__ void xcd_tile(int& bx, int& by) {
  int gx = gridDim.x;
  int nwg = gx * gridDim.y;
  int id = blockIdx.y * gx + blockIdx.x;
  int tile = (id & 7) * (nwg >> 3) + (id >> 3);
  bx = tile % gx;
  by = tile / gx;
}

// ---------------- block-wide sum reduction (256 threads = 4 waves) ----------
__device__ __forceinline__ float block_sum(float v, float* sbuf) {
#pragma unroll
  for (int o = 32; o > 0; o >>= 1) v += __shfl_down(v, o, 64);
  int lane = threadIdx.x & 63, wid = threadIdx.x >> 6;
  if (lane == 0) sbuf[wid] = v;
  __syncthreads();
  if (threadIdx.x == 0) {
    float t = 0.f;
    for (int i = 0; i < 4; i++) t += sbuf[i];
    sbuf[0] = t;
  }
  __syncthreads();
  return sbuf[0];
}

// ---------------- LN over 512 -> bf16 (device body) -------------------------
__device__ __forceinline__ void ln512_body(
    const float* __restrict__ x, const float* __restrict__ w,
    const float* __restrict__ b, bf16* __restrict__ out, int row,
    float* s1, float* s2) {
  const float* xr = x + (size_t)row * D_MODEL;
  bf16* outr = out + (size_t)row * D_MODEL;
  int c0 = threadIdx.x, c1 = threadIdx.x + 256;
  float v0 = xr[c0], v1 = xr[c1];
  float s  = block_sum(v0 + v1, s1);
  float ss = block_sum(v0 * v0 + v1 * v1, s2);
  float mean = s * (1.f / 512.f);
  float var  = ss * (1.f / 512.f) - mean * mean;
  float inv  = rsqrtf(var + 1e-5f);
  outr[c0] = __float2bfloat16((v0 - mean) * inv * w[c0] + b[c0]);
  outr[c1] = __float2bfloat16((v1 - mean) * inv * w[c1] + b[c1]);
}

__global__ __launch_bounds__(256) void ln512_bf16_kernel(
    const float* __restrict__ x, const float* __restrict__ w,
    const float* __restrict__ b, bf16* __restrict__ out) {
  __shared__ float s1[8], s2[8];
  ln512_body(x, w, b, out, blockIdx.x, s1, s2);
}

// ---------------- prep: weight converts (3136 blocks) + LN1 (8192 blocks) ---
__global__ __launch_bounds__(256) void prep_kernel(
    const float* __restrict__ in_w, bf16* __restrict__ in_wt,
    const float* __restrict__ out_w, bf16* __restrict__ out_wt,
    const float* __restrict__ ff1_w, bf16* __restrict__ ff1_wt,
    const float* __restrict__ ff2_w, bf16* __restrict__ ff2_wt,
    const float* __restrict__ x, const float* __restrict__ ln1_w,
    const float* __restrict__ ln1_b, bf16* __restrict__ xnb) {
  __shared__ float tile[32][33];
  int id = blockIdx.x;
  if (id >= 3136) {  // LN1 part
    ln512_body(x, ln1_w, ln1_b, xnb, id - 3136, &tile[0][0], &tile[1][0]);
    return;
  }
  const float* w; bf16* wt;
  int K, N, Npad, bx, by;
  if (id < 1088)      { w = in_w;  wt = in_wt;  K = 512;  N = NPROJ; Npad = 2176; bx = id % 68;  by = id / 68; }
  else if (id < 1600) { int j = id - 1088; w = out_w; wt = out_wt; K = 1024; N = 512;  Npad = 512;  bx = j % 16; by = j / 16; }
  else if (id < 2624) { int j = id - 1600; w = ff1_w; wt = ff1_wt; K = 512;  N = 2048; Npad = 2048; bx = j % 64; by = j / 64; }
  else                { int j = id - 2624; w = ff2_w; wt = ff2_wt; K = 1024; N = 512;  Npad = 512;  bx = j % 16; by = j / 16; }
  int n0 = bx * 32, k0 = by * 32;
  int tx = threadIdx.x & 31, ty = threadIdx.x >> 5;  // 32 x 8
#pragma unroll
  for (int i = 0; i < 4; i++) {
    int k = k0 + ty + i * 8, n = n0 + tx;
    tile[ty + i * 8][tx] = (k < K && n < N) ? w[(size_t)k * N + n] : 0.f;
  }
  __syncthreads();
#pragma unroll
  for (int i = 0; i < 4; i++) {
    int n = n0 + ty + i * 8, k = k0 + tx;
    if (n < Npad && k < K)
      wt[(size_t)n * K + k] = __float2bfloat16(tile[tx][ty + i * 8]);
  }
}

// ---------------- fp32-out MFMA GEMM, 3-buffer counted-vmcnt + T1 swizzle ---
template<int BM, int BN, int WN, int MR, int NR>
__global__ __launch_bounds__(256) void mfma_gemm_kernel(
    const bf16* __restrict__ A, const bf16* __restrict__ Bt,
    const float* __restrict__ bias, int nbias,
    const float* __restrict__ resid,
    float* __restrict__ C, int ldc, int K) {
  constexpr int ROWS = BM + BN;
  constexpr int ISS  = ROWS / 64;
  __shared__ __align__(16) bf16 sAB[3][ROWS][32];

  int wid = threadIdx.x >> 6, lane = threadIdx.x & 63;
  int bx, by;
  xcd_tile(bx, by);
  int row0 = by * BM, col0 = bx * BN;
  int wr = (wid / WN) * (MR * 16);
  int wc = (wid % WN) * (NR * 16);
  int lr = lane >> 2;
  int lc = (lane & 3) * 8;

  f32x4 acc[MR][NR];
#pragma unroll
  for (int m = 0; m < MR; m++)
#pragma unroll
    for (int n = 0; n < NR; n++) acc[m][n] = (f32x4){0.f, 0.f, 0.f, 0.f};

  auto stage = [&](int buf, int k0) {
#pragma unroll
    for (int i = 0; i < ISS; i++) {
      int rb = (wid * ISS + i) * 16;
      int r = rb + lr;
      const bf16* src = (r < BM)
          ? A  + (size_t)(row0 + r) * K + k0 + lc
          : Bt + (size_t)(col0 + (r - BM)) * K + k0 + lc;
      __builtin_amdgcn_global_load_lds(
          (const __attribute__((address_space(1))) void*)src,
          (__attribute__((address_space(3))) void*)&sAB[buf][rb][0], 16, 0, 0);
    }
  };

  stage(0, 0);
  stage(1, 32);
  int cur = 0;
  for (int k0 = 0; k0 < K; k0 += 32) {
    if (k0 + 32 < K) vmwait<ISS>(); else vmwait<0>();
    __builtin_amdgcn_s_barrier();
    asm volatile("" ::: "memory");
    if (k0 + 64 < K) stage(cur == 0 ? 2 : cur - 1, k0 + 64);
    short8 a[MR], b[NR];
    int kk = (lane >> 4) * 8;
#pragma unroll
    for (int m = 0; m < MR; m++)
      a[m] = *(const short8*)&sAB[cur][wr + m * 16 + (lane & 15)][kk];
#pragma unroll
    for (int n = 0; n < NR; n++)
      b[n] = *(const short8*)&sAB[cur][BM + wc + n * 16 + (lane & 15)][kk];
#pragma unroll
    for (int m = 0; m < MR; m++)
#pragma unroll
      for (int n = 0; n < NR; n++)
        acc[m][n] = __builtin_amdgcn_mfma_f32_16x16x32_bf16(a[m], b[n], acc[m][n], 0, 0, 0);
    asm volatile("" ::: "memory");
    cur = (cur == 2) ? 0 : cur + 1;
  }

  int crow = row0 + wr + (lane >> 4) * 4;
  int ccol = col0 + wc + (lane & 15);
#pragma unroll
  for (int m = 0; m < MR; m++) {
#pragma unroll
    for (int n = 0; n < NR; n++) {
      int colg = ccol + n * 16;
      float bv = bias ? ((colg < nbias) ? bias[colg] : 0.f) : 0.f;
#pragma unroll
      for (int j = 0; j < 4; j++) {
        int rowg = crow + m * 16 + j;
        float v = acc[m][n][j] + bv;
        if (resid) v += resid[(size_t)rowg * ldc + colg];
        C[(size_t)rowg * ldc + colg] = v;
      }
    }
  }
}

// ---------------- in-proj GEMM (3-buf + T1): z->zb, x->xsc, aux -------------
__global__ __launch_bounds__(256) void inproj_gemm_kernel(
    const bf16* __restrict__ A, const bf16* __restrict__ Bt,
    const float* __restrict__ bias,
    bf16* __restrict__ zb, bf16* __restrict__ xsc,
    float* __restrict__ aux, int K) {
  constexpr int BM = 128, ROWS = 256, ISS = 4;
  __shared__ __align__(16) bf16 sAB[3][ROWS][32];

  int wid = threadIdx.x >> 6, lane = threadIdx.x & 63;
  int bx, by;
  xcd_tile(bx, by);
  int row0 = by * BM, col0 = bx * 128;
  int wr = (wid >> 1) * 64;
  int wc = (wid & 1) * 64;
  int lr = lane >> 2;
  int lc = (lane & 3) * 8;

  f32x4 acc[4][4];
#pragma unroll
  for (int m = 0; m < 4; m++)
#pragma unroll
    for (int n = 0; n < 4; n++) acc[m][n] = (f32x4){0.f, 0.f, 0.f, 0.f};

  auto stage = [&](int buf, int k0) {
#pragma unroll
    for (int i = 0; i < ISS; i++) {
      int rb = (wid * ISS + i) * 16;
      int r = rb + lr;
      const bf16* src = (r < BM)
          ? A  + (size_t)(row0 + r) * K + k0 + lc
          : Bt + (size_t)(col0 + (r - BM)) * K + k0 + lc;
      __builtin_amdgcn_global_load_lds(
          (const __attribute__((address_space(1))) void*)src,
          (__attribute__((address_space(3))) void*)&sAB[buf][rb][0], 16, 0, 0);
    }
  };

  stage(0, 0);
  stage(1, 32);
  int cur = 0;
  for (int k0 = 0; k0 < K; k0 += 32) {
    if (k0 + 32 < K) vmwait<ISS>(); else vmwait<0>();
    __builtin_amdgcn_s_barrier();
    asm volatile("" ::: "memory");
    if (k0 + 64 < K) stage(cur == 0 ? 2 : cur - 1, k0 + 64);
    short8 a[4], b[4];
    int kk = (lane >> 4) * 8;
#pragma unroll
    for (int m = 0; m < 4; m++)
      a[m] = *(const short8*)&sAB[cur][wr + m * 16 + (lane & 15)][kk];
#pragma unroll
    for (int n = 0; n < 4; n++)
      b[n] = *(const short8*)&sAB[cur][BM + wc + n * 16 + (lane & 15)][kk];
#pragma unroll
    for (int m = 0; m < 4; m++)
#pragma unroll
      for (int n = 0; n < 4; n++)
        acc[m][n] = __builtin_amdgcn_mfma_f32_16x16x32_bf16(a[m], b[n], acc[m][n], 0, 0, 0);
    asm volatile("" ::: "memory");
    cur = (cur == 2) ? 0 : cur + 1;
  }

  int crow = row0 + wr + (lane >> 4) * 4;
  int ccol = col0 + wc + (lane & 15);
#pragma unroll
  for (int m = 0; m < 4; m++) {
#pragma unroll
    for (int n = 0; n < 4; n++) {
      int colg = ccol + n * 16;
      float bv = (colg < NPROJ) ? bias[colg] : 0.f;
#pragma unroll
      for (int j = 0; j < 4; j++) {
        int rowg = crow + m * 16 + j;
        float v = acc[m][n][j] + bv;
        if (colg < 1024) {
          zb[(size_t)rowg * 1024 + colg] = __float2bfloat16(v);
        } else if (colg < 2048) {
          // scan layout: [b][h][ps][t][w*16+pl]
          int cx = colg - 1024;
          int h = cx >> 6, p = cx & 63;
          int bb = rowg >> 10, t = (rowg >> 4) & 63, w = rowg & 15;
          size_t idx = ((((size_t)bb * 16 + h) * 4 + (p >> 4)) * 64 + t) * 256
                     + w * 16 + (p & 15);
          xsc[idx] = __float2bfloat16(v);
        } else if (colg < 2112) {
          aux[(size_t)rowg * 64 + (colg - 2048)] = v;
        }
      }
    }
  }
}

// ---------------- FF1 GEMM + SiLU gate (3-buf + T1) -> bf16 -----------------
__global__ __launch_bounds__(256) void ff1_fused_kernel(
    const bf16* __restrict__ A, const bf16* __restrict__ Bt,
    const float* __restrict__ bias, bf16* __restrict__ out, int K) {
  constexpr int BM = 128, ROWS = 384, ISS = 6;
  __shared__ __align__(16) bf16 sAB[3][ROWS][32];

  int wid = threadIdx.x >> 6, lane = threadIdx.x & 63;
  int bx, by;
  xcd_tile(bx, by);
  int row0 = by * BM, col0 = bx * 128;
  int wr = (wid >> 1) * 64;
  int wc = (wid & 1) * 64;
  int lr = lane >> 2;
  int lc = (lane & 3) * 8;

  f32x4 acc1[4][4], acc2[4][4];
#pragma unroll
  for (int m = 0; m < 4; m++)
#pragma unroll
    for (int n = 0; n < 4; n++) {
      acc1[m][n] = (f32x4){0.f, 0.f, 0.f, 0.f};
      acc2[m][n] = (f32x4){0.f, 0.f, 0.f, 0.f};
    }

  auto stage = [&](int buf, int k0) {
#pragma unroll
    for (int i = 0; i < ISS; i++) {
      int rb = (wid * ISS + i) * 16;
      int r = rb + lr;
      const bf16* src;
      if (r < BM)       src = A  + (size_t)(row0 + r) * K + k0 + lc;
      else if (r < 256) src = Bt + (size_t)(col0 + (r - 128)) * K + k0 + lc;
      else              src = Bt + (size_t)(1024 + col0 + (r - 256)) * K + k0 + lc;
      __builtin_amdgcn_global_load_lds(
          (const __attribute__((address_space(1))) void*)src,
          (__attribute__((address_space(3))) void*)&sAB[buf][rb][0], 16, 0, 0);
    }
  };

  stage(0, 0);
  stage(1, 32);
  int cur = 0;
  for (int k0 = 0; k0 < K; k0 += 32) {
    if (k0 + 32 < K) vmwait<ISS>(); else vmwait<0>();
    __builtin_amdgcn_s_barrier();
    asm volatile("" ::: "memory");
    if (k0 + 64 < K) stage(cur == 0 ? 2 : cur - 1, k0 + 64);
    short8 a[4], b1[4], b2[4];
    int kk = (lane >> 4) * 8;
#pragma unroll
    for (int m = 0; m < 4; m++)
      a[m] = *(const short8*)&sAB[cur][wr + m * 16 + (lane & 15)][kk];
#pragma unroll
    for (int n = 0; n < 4; n++) {
      b1[n] = *(const short8*)&sAB[cur][128 + wc + n * 16 + (lane & 15)][kk];
      b2[n] = *(const short8*)&sAB[cur][256 + wc + n * 16 + (lane & 15)][kk];
    }
#pragma unroll
    for (int m = 0; m < 4; m++)
#pragma unroll
      for (int n = 0; n < 4; n++) {
        acc1[m][n] = __builtin_amdgcn_mfma_f32_16x16x32_bf16(a[m], b1[n], acc1[m][n], 0, 0, 0);
        acc2[m][n] = __builtin_amdgcn_mfma_f32_16x16x32_bf16(a[m], b2[n], acc2[m][n], 0, 0, 0);
      }
    asm volatile("" ::: "memory");
    cur = (cur == 2) ? 0 : cur + 1;
  }

  int crow = row0 + wr + (lane >> 4) * 4;
  int ccol = col0 + wc + (lane & 15);
#pragma unroll
  for (int m = 0; m < 4; m++) {
#pragma unroll
    for (int n = 0; n < 4; n++) {
      int colg = ccol + n * 16;
      float bv1 = bias[colg];
      float bv2 = bias[1024 + colg];
#pragma unroll
      for (int j = 0; j < 4; j++) {
        int rowg = crow + m * 16 + j;
        float f1 = acc1[m][n][j] + bv1;
        float g  = acc2[m][n][j] + bv2;
        float sg = g / (1.f + expf(-g));
        out[(size_t)rowg * 1024 + colg] = __float2bfloat16(f1 * sg);
      }
    }
  }
}

// ---------------- tree scan: coalesced x + T14 prefetch, 16-step chunks -----
// lane = (w, q): w = lane>>2, pl = wid*4 + q. State h[16] fp32 in VGPRs;
// cross-w transport packs 2 states per bpermute word (bf16).
// 4 chunks x 16 steps: half the barriers of the 8x8 version; dt staging
// uses all 256 threads (no tid<128 divergence).
__global__ __launch_bounds__(256) void tree_scan_kernel(
    const bf16* __restrict__ xsc, const float* __restrict__ aux,
    const int* __restrict__ parent,
    const float* __restrict__ A_log, const float* __restrict__ dt_bias,
    const float* __restrict__ Dp, bf16* __restrict__ y) {
  const int tid = threadIdx.x;
  const int ps = blockIdx.x & 3;
  const int h  = (blockIdx.x >> 2) & 15;
  const int b  = blockIdx.x >> 6;
  const int wid = tid >> 6;
  const int lane = tid & 63;
  const int w = lane >> 2;
  const int q = lane & 3;
  const int pl = wid * 4 + q;

  __shared__ __align__(16) u32   BCs[16][16][20];
  __shared__ __align__(16) float dAs[16][16];
  __shared__ __align__(16) float dtss[16][16];
  __shared__ __align__(16) int   pars[16][16];

  const float Ah  = -expf(A_log[h]);
  const float dtb = dt_bias[h];
  const float Dh  = Dp[h];
  const u16* xp = (const u16*)xsc
      + ((((size_t)b * 16 + h) * 4 + ps) * 64) * 256 + w * 16 + pl;
  const int ycol = (h << 6) + (ps << 4) + pl;

  float hst[16];
#pragma unroll
  for (int n = 0; n < 16; n++) hst[n] = 0.f;

  // staging maps: B/C 512 tasks over 2 rounds; dt 256 tasks (all threads)
  const int dt_t = tid >> 4, dt_w = tid & 15;

  u16 xpre[16];
  float4 bcr[2][4];
  float dtpre = 0.f;
  int papre = 0;

  auto issue = [&](int c) {
    const int t0 = c * 16;
#pragma unroll
    for (int tt = 0; tt < 16; tt++) xpre[tt] = xp[(size_t)(t0 + tt) * 256];
#pragma unroll
    for (int r = 0; r < 2; r++) {
      int idx = tid + (r << 8);
      int t = idx >> 5, wv = (idx >> 1) & 15, hf = idx & 1;
      size_t row = ((size_t)(b * NT + t0 + t)) * NW + wv;
      const float* src = aux + row * 64 + hf * 16;
      bcr[r][0] = *(const float4*)&src[0];
      bcr[r][1] = *(const float4*)&src[4];
      bcr[r][2] = *(const float4*)&src[8];
      bcr[r][3] = *(const float4*)&src[12];
    }
    size_t r2 = ((size_t)(b * NT + t0 + dt_t)) * NW + dt_w;
    dtpre = aux[r2 * 64 + 32 + h];
    papre = parent[r2];
  };

  issue(0);
  for (int c = 0; c < 4; c++) {
    const int t0 = c * 16;
    __syncthreads();  // previous chunk's compute done (LDS free)
    float xv[16];
#pragma unroll
    for (int tt = 0; tt < 16; tt++) xv[tt] = ubits((u32)xpre[tt] << 16);
    {
      float dtr = dtpre + dtb;
      float dtv = (dtr > 20.f) ? dtr : log1pf(expf(dtr));
      dtss[dt_w][dt_t] = dtv;
      dAs[dt_w][dt_t]  = expf(dtv * Ah);
      pars[dt_w][dt_t] = papre;
    }
#pragma unroll
    for (int r = 0; r < 2; r++) {
      int idx = tid + (r << 8);
      int t = idx >> 5, wv = (idx >> 1) & 15, hf = idx & 1;
      float4 v0 = bcr[r][0], v1 = bcr[r][1], v2 = bcr[r][2], v3 = bcr[r][3];
      uint4 p0 = {pack_bf(v0.x, v0.y), pack_bf(v0.z, v0.w),
                  pack_bf(v1.x, v1.y), pack_bf(v1.z, v1.w)};
      uint4 p1 = {pack_bf(v2.x, v2.y), pack_bf(v2.z, v2.w),
                  pack_bf(v3.x, v3.y), pack_bf(v3.z, v3.w)};
      *(uint4*)&BCs[t][wv][hf * 8]     = p0;
      *(uint4*)&BCs[t][wv][hf * 8 + 4] = p1;
    }
    __syncthreads();  // staging visible
    float dAr[16], dtr16[16];
    int parr[16];
#pragma unroll
    for (int i = 0; i < 4; i++) {
      *(float4*)&dAr[i * 4]   = *(const float4*)&dAs[w][i * 4];
      *(float4*)&dtr16[i * 4] = *(const float4*)&dtss[w][i * 4];
      *(int4*)&parr[i * 4]    = *(const int4*)&pars[w][i * 4];
    }
    if (c < 3) issue(c + 1);

#pragma unroll
    for (int tt = 0; tt < 16; tt++) {
      float dA  = dAr[tt];
      float dtx = dtr16[tt] * xv[tt];
      int   par = parr[tt];
      int gidx = (((par << 2) | q) << 2);
      u32 pk[8];
#pragma unroll
      for (int i = 0; i < 8; i++)
        pk[i] = (u32)__builtin_amdgcn_ds_bpermute(
            gidx, (int)pack_bf(hst[2 * i], hst[2 * i + 1]));
      uint4 bA = *(const uint4*)&BCs[tt][w][0];
      uint4 bB = *(const uint4*)&BCs[tt][w][4];
      uint4 cA = *(const uint4*)&BCs[tt][w][8];
      uint4 cB = *(const uint4*)&BCs[tt][w][12];
      u32 bwv[8] = {bA.x, bA.y, bA.z, bA.w, bB.x, bB.y, bB.z, bB.w};
      u32 cwv[8] = {cA.x, cA.y, cA.z, cA.w, cB.x, cB.y, cB.z, cB.w};
      float yv = 0.f;
#pragma unroll
      for (int i = 0; i < 8; i++) {
        u32 g = pk[i], bu = bwv[i], cu = cwv[i];
        float hp0 = ubits(g << 16);
        float hp1 = ubits(g & 0xffff0000u);
        float bl  = ubits(bu << 16), bh  = ubits(bu & 0xffff0000u);
        float cl  = ubits(cu << 16), ch  = ubits(cu & 0xffff0000u);
        float h0 = fmaf(dA, hp0, dtx * bl);
        float h1 = fmaf(dA, hp1, dtx * bh);
        hst[2 * i] = h0;
        hst[2 * i + 1] = h1;
        yv = fmaf(h0, cl, fmaf(h1, ch, yv));
      }
      size_t row = ((size_t)(b * NT + t0 + tt)) * NW + w;
      y[row * D_INNER + ycol] = __float2bfloat16(fmaf(Dh, xv[tt], yv));
    }
  }
}

// ---------------- gated RMSNorm (bf16 in/out, compact z) --------------------
__global__ __launch_bounds__(256) void gate_rms_kernel(
    const bf16* __restrict__ yin, const bf16* __restrict__ zb,
    const float* __restrict__ norm_w, bf16* __restrict__ out) {
  __shared__ float sbuf[8];
  int row = blockIdx.x;
  const bf16* yr = yin + (size_t)row * D_INNER;
  const bf16* zr = zb + (size_t)row * D_INNER;
  int c = threadIdx.x * 4;
  bf16 y4[4], z4[4];
  *(uint2*)y4 = *(const uint2*)&yr[c];
  *(uint2*)z4 = *(const uint2*)&zr[c];
  float gv[4];
  float ss = 0.f;
#pragma unroll
  for (int j = 0; j < 4; j++) {
    float z = __bfloat162float(z4[j]);
    float t = __bfloat162float(y4[j]) * (z / (1.f + expf(-z)));
    gv[j] = t;
    ss += t * t;
  }
  ss = block_sum(ss, sbuf);
  float scale = rsqrtf(ss * (1.f / 1024.f) + 1e-5f);
  bf16 o4[4];
#pragma unroll
  for (int j = 0; j < 4; j++) o4[j] = __float2bfloat16(gv[j] * scale * norm_w[c + j]);
  *(uint2*)&out[(size_t)row * D_INNER + c] = *(uint2*)o4;
}

extern "C" void kernel_launch(void* const* d_in, const int* in_sizes, int n_in,
                              void* d_out, int out_size, void* d_ws, size_t ws_size,
                              hipStream_t stream) {
  const float* x       = (const float*)d_in[0];
  const int*   parent  = (const int*)d_in[1];
  const float* ln1_w   = (const float*)d_in[2];
  const float* ln1_b   = (const float*)d_in[3];
  const float* in_w    = (const float*)d_in[4];
  const float* in_b    = (const float*)d_in[5];
  const float* A_log   = (const float*)d_in[6];
  const float* dt_bias = (const float*)d_in[7];
  const float* Dp      = (const float*)d_in[8];
  const float* norm_w  = (const float*)d_in[9];
  const float* out_w   = (const float*)d_in[10];
  const float* out_b   = (const float*)d_in[11];
  const float* ln2_w   = (const float*)d_in[12];
  const float* ln2_b   = (const float*)d_in[13];
  const float* ff1_w   = (const float*)d_in[14];
  const float* ff1_b   = (const float*)d_in[15];
  const float* ff2_w   = (const float*)d_in[16];
  const float* ff2_b   = (const float*)d_in[17];
  float* outp = (float*)d_out;

  char* wp = (char*)d_ws;
  bf16* xnb    = (bf16*)wp;  wp += (size_t)MROWS * D_MODEL * 2;
  bf16* in_wt  = (bf16*)wp;  wp += (size_t)2176 * D_MODEL * 2;
  bf16* out_wt = (bf16*)wp;  wp += (size_t)D_MODEL * D_INNER * 2;
  bf16* ff1_wt = (bf16*)wp;  wp += (size_t)2048 * D_MODEL * 2;
  bf16* ff2_wt = (bf16*)wp;  wp += (size_t)D_MODEL * D_INNER * 2;
  bf16* zb     = (bf16*)wp;  wp += (size_t)MROWS * D_INNER * 2;
  bf16* xsc    = (bf16*)wp;  wp += (size_t)MROWS * D_INNER * 2;
  float* aux   = (float*)wp; wp += (size_t)MROWS * 64 * 4;
  bf16* yb     = (bf16*)wp;  wp += (size_t)MROWS * D_INNER * 2;
  bf16* ygb    = (bf16*)wp;  wp += (size_t)MROWS * D_INNER * 2;
  float* xmid  = outp;  // d_out doubles as xmid

  dim3 blk(256);
  // 0) weight converts + LN1 in ONE dispatch (independent work, co-scheduled)
  prep_kernel<<<3136 + MROWS, blk, 0, stream>>>(
      in_w, in_wt, out_w, out_wt, ff1_w, ff1_wt, ff2_w, ff2_wt,
      x, ln1_w, ln1_b, xnb);
  // 1) in-proj GEMM -> zb + xsc (scan layout) + aux
  inproj_gemm_kernel<<<dim3(2176 / 128, MROWS / 128), blk, 0, stream>>>(
      xnb, in_wt, in_b, zb, xsc, aux, D_MODEL);
  // 2) tree scan -> yb (bf16)
  tree_scan_kernel<<<NB * NHEAD * 4, blk, 0, stream>>>(xsc, aux, parent,
                                                       A_log, dt_bias, Dp, yb);
  // 3) gated RMSNorm -> ygb (bf16)
  gate_rms_kernel<<<MROWS, blk, 0, stream>>>(yb, zb, norm_w, ygb);
  // 4) out-proj GEMM + resid(x) -> xmid (fp32)
  mfma_gemm_kernel<64, 128, 4, 4, 2><<<dim3(D_MODEL / 128, MROWS / 64), blk, 0, stream>>>(
      ygb, out_wt, out_b, D_MODEL, x, xmid, D_MODEL, D_INNER);
  // 5) LN2 -> xnb
  ln512_bf16_kernel<<<MROWS, blk, 0, stream>>>(xmid, ln2_w, ln2_b, xnb);
  // 6) FF1 GEMM + SiLU gate fused -> yb (reuse)
  ff1_fused_kernel<<<dim3(8, MROWS / 128), blk, 0, stream>>>(
      xnb, ff1_wt, ff1_b, yb, D_MODEL);
  // 7) FF2 GEMM + resid(xmid) -> d_out
  mfma_gemm_kernel<64, 128, 4, 4, 2><<<dim3(D_MODEL / 128, MROWS / 64), blk, 0, stream>>>(
      yb, ff2_wt, ff2_b, D_MODEL, xmid, outp, D_MODEL, D_INNER);
}